// Round 2
// baseline (183.446 us; speedup 1.0000x reference)
//
#include <hip/hip_runtime.h>

// SimpleGCNConv: out = rownorm(setadj(edge_index) + I) @ x @ W^T + b
// N=8192, E=262144, D_IN=D_OUT=128. All float tensors are fp32 (as the
// reference declares); edge_index is int32 per the harness contract.
// Dedup via dense bitmap (8192x8192 bits = 8 MB in d_ws) because duplicate
// edges must count ONCE (.set semantics), and self-loop is added ON TOP.

typedef unsigned int uint32;

#define NNODES 8192
#define DF 128
#define WORDS_PER_ROW (NNODES / 32)   // 256

__global__ void edge_scatter(const int* __restrict__ ei, int E,
                             uint32* __restrict__ bm) {
    int e = blockIdx.x * blockDim.x + threadIdx.x;
    if (e >= E) return;
    int src = ei[e];        // edge_index[0][e]
    int dst = ei[E + e];    // edge_index[1][e]
    atomicOr(&bm[(size_t)src * WORDS_PER_ROW + (dst >> 5)], 1u << (dst & 31));
}

// One block (128 threads) per node. Thread t owns feature/output dim t.
__global__ __launch_bounds__(128) void agg_linear(
    const float* __restrict__ x,
    const uint32* __restrict__ bm,
    const float* __restrict__ W,
    const float* __restrict__ b,
    float* __restrict__ out)
{
    __shared__ uint32 row[WORDS_PER_ROW];
    __shared__ float agg[DF];

    const int i = blockIdx.x;
    const int t = threadIdx.x;

    // Stage this node's bitmap row into LDS (coalesced).
    row[t]       = bm[(size_t)i * WORDS_PER_ROW + t];
    row[t + 128] = bm[(size_t)i * WORDS_PER_ROW + t + 128];
    __syncthreads();

    // Self-loop from the identity (added on top of the set-adjacency;
    // if edge (i,i) exists its bit adds x[i] once more and deg once more,
    // matching adj[i,i] = 2 in the reference).
    float acc = x[(size_t)i * DF + t];
    int deg = 1;

    // Uniform scan: every lane sees the same word -> broadcast, no divergence.
    for (int w = 0; w < WORDS_PER_ROW; ++w) {
        uint32 word = row[w];
        if (word == 0u) continue;
        deg += __popc(word);
        int base = w << 5;
        while (word) {
            int bit = __ffs(word) - 1;
            word &= word - 1;
            acc += x[(size_t)(base + bit) * DF + t];
        }
    }

    acc /= (float)deg;
    agg[t] = acc;
    __syncthreads();

    // Fused linear: out[i][t] = b[t] + sum_d agg[d] * W[t][d]
    const float4* Wrow = (const float4*)(W + (size_t)t * DF);
    float sum = b[t];
    #pragma unroll
    for (int c = 0; c < DF / 4; ++c) {
        float4 wv = Wrow[c];
        sum += wv.x * agg[c * 4 + 0] + wv.y * agg[c * 4 + 1]
             + wv.z * agg[c * 4 + 2] + wv.w * agg[c * 4 + 3];
    }
    out[(size_t)i * DF + t] = sum;
}

extern "C" void kernel_launch(void* const* d_in, const int* in_sizes, int n_in,
                              void* d_out, int out_size, void* d_ws, size_t ws_size,
                              hipStream_t stream) {
    const float* x = (const float*)d_in[0];
    const int*  ei = (const int*)d_in[1];
    const float* W = (const float*)d_in[2];
    const float* b = (const float*)d_in[3];
    float* out = (float*)d_out;

    uint32* bm = (uint32*)d_ws;
    const int E = in_sizes[1] / 2;

    // d_ws is re-poisoned to 0xAA before every launch: zero the bitmap.
    hipMemsetAsync(bm, 0, (size_t)NNODES * WORDS_PER_ROW * sizeof(uint32), stream);

    edge_scatter<<<dim3((E + 255) / 256), dim3(256), 0, stream>>>(ei, E, bm);
    agg_linear<<<dim3(NNODES), dim3(128), 0, stream>>>(x, bm, W, b, out);
}

// Round 3
// 105.646 us; speedup vs baseline: 1.7364x; 1.7364x over previous
//
#include <hip/hip_runtime.h>

// SimpleGCNConv: out = rownorm(setadj(edge_index) + I) @ x @ W^T + b
// N=8192, E=262144, D=128, fp32. Dedup via dense bitmap (8 MB in d_ws);
// duplicate edges count ONCE (.set), self-loop added ON TOP.
//
// R3: compact bitmap row -> LDS neighbor list (parallel bit-extract,
// LDS atomicAdd offsets), then gather with independent unrolled loads.
// M=4 nodes/block amortizes the 64 KB W re-read and adds MLP.

typedef unsigned int uint32;

#define NNODES 8192
#define DF 128
#define WPR 256        // bitmap words per row
#define M 4            // nodes per block
#define CAP 384        // LDS list capacity per node (mean deg 32, ~60 sigma)

__global__ void edge_scatter(const int* __restrict__ ei, int E,
                             uint32* __restrict__ bm) {
    int e = blockIdx.x * blockDim.x + threadIdx.x;
    if (e >= E) return;
    int src = ei[e];        // edge_index[0][e]
    int dst = ei[E + e];    // edge_index[1][e]
    atomicOr(&bm[(size_t)src * WPR + (dst >> 5)], 1u << (dst & 31));
}

__global__ __launch_bounds__(128) void gcn_fused(
    const float* __restrict__ x,
    const uint32* __restrict__ bm,
    const float* __restrict__ W,
    const float* __restrict__ b,
    float* __restrict__ out)
{
    __shared__ int   nbr[M][CAP];
    __shared__ int   total[M];
    __shared__ float agg[M][DF];

    const int t = threadIdx.x;
    const int node0 = blockIdx.x * M;

    if (t < M) total[t] = 0;
    __syncthreads();

    // ---- Phase A: build neighbor lists for M nodes (parallel bit-extract).
    for (int m = 0; m < M; ++m) {
        const uint32* r = bm + (size_t)(node0 + m) * WPR;
        uint32 w0 = r[2 * t];
        uint32 w1 = r[2 * t + 1];
        int c = __popc(w0) + __popc(w1);
        if (c) {
            int off = atomicAdd(&total[m], c);
            int base0 = (2 * t) << 5, base1 = (2 * t + 1) << 5;
            while (w0) {
                int bit = __ffs(w0) - 1; w0 &= w0 - 1;
                if (off < CAP) nbr[m][off] = base0 + bit;
                off++;
            }
            while (w1) {
                int bit = __ffs(w1) - 1; w1 &= w1 - 1;
                if (off < CAP) nbr[m][off] = base1 + bit;
                off++;
            }
        }
    }
    __syncthreads();

    // ---- Phase B: gather. Thread t owns feature t; M independent chains.
    float acc[M];
    #pragma unroll
    for (int m = 0; m < M; ++m) acc[m] = x[(size_t)(node0 + m) * DF + t]; // eye

    #pragma unroll
    for (int m = 0; m < M; ++m) {
        int cnt = total[m];
        if (cnt <= CAP) {
            int k = 0;
            for (; k + 4 <= cnt; k += 4) {
                int j0 = nbr[m][k], j1 = nbr[m][k + 1],
                    j2 = nbr[m][k + 2], j3 = nbr[m][k + 3];
                float a0 = x[(size_t)j0 * DF + t];
                float a1 = x[(size_t)j1 * DF + t];
                float a2 = x[(size_t)j2 * DF + t];
                float a3 = x[(size_t)j3 * DF + t];
                acc[m] += (a0 + a1) + (a2 + a3);
            }
            for (; k < cnt; ++k) acc[m] += x[(size_t)nbr[m][k] * DF + t];
        } else {
            // Overflow fallback (statistically never taken; correctness-safe):
            // uniform rescan of the bitmap row from global (broadcast reads).
            const uint32* r = bm + (size_t)(node0 + m) * WPR;
            for (int w = 0; w < WPR; ++w) {
                uint32 word = r[w];
                int base = w << 5;
                while (word) {
                    int bit = __ffs(word) - 1; word &= word - 1;
                    acc[m] += x[(size_t)(base + bit) * DF + t];
                }
            }
        }
        agg[m][t] = acc[m] / (float)(1 + cnt);   // +1: self-loop on top
    }
    __syncthreads();

    // ---- Phase C: linear. Thread t owns out dim t for all M nodes;
    // W row t read once (float4), reused across M.
    const float4* Wrow = (const float4*)(W + (size_t)t * DF);
    float bias = b[t];
    float sum[M];
    #pragma unroll
    for (int m = 0; m < M; ++m) sum[m] = bias;

    #pragma unroll 8
    for (int c4 = 0; c4 < DF / 4; ++c4) {
        float4 wv = Wrow[c4];
        #pragma unroll
        for (int m = 0; m < M; ++m) {
            sum[m] += wv.x * agg[m][c4 * 4 + 0] + wv.y * agg[m][c4 * 4 + 1]
                    + wv.z * agg[m][c4 * 4 + 2] + wv.w * agg[m][c4 * 4 + 3];
        }
    }
    #pragma unroll
    for (int m = 0; m < M; ++m)
        out[(size_t)(node0 + m) * DF + t] = sum[m];
}

extern "C" void kernel_launch(void* const* d_in, const int* in_sizes, int n_in,
                              void* d_out, int out_size, void* d_ws, size_t ws_size,
                              hipStream_t stream) {
    const float* x = (const float*)d_in[0];
    const int*  ei = (const int*)d_in[1];
    const float* W = (const float*)d_in[2];
    const float* b = (const float*)d_in[3];
    float* out = (float*)d_out;

    uint32* bm = (uint32*)d_ws;
    const int E = in_sizes[1] / 2;

    // d_ws is re-poisoned before every launch: zero the bitmap.
    hipMemsetAsync(bm, 0, (size_t)NNODES * WPR * sizeof(uint32), stream);

    edge_scatter<<<dim3((E + 255) / 256), dim3(256), 0, stream>>>(ei, E, bm);
    gcn_fused<<<dim3(NNODES / M), dim3(128), 0, stream>>>(x, bm, W, b, out);
}

// Round 4
// 100.642 us; speedup vs baseline: 1.8228x; 1.0497x over previous
//
#include <hip/hip_runtime.h>

// SimpleGCNConv: out = rownorm(setadj(edge_index) + I) @ x @ W^T + b
// N=8192, E=262144, D=128, fp32. Dedup via dense bitmap (8 MB in d_ws);
// duplicate edges count ONCE (.set), self-loop added ON TOP.
//
// R4: Phase A uses wave prefix-sum (no LDS atomics). Phase B gathers
// float4 (32 lanes/row, 4 rows/wave-instr) with the M node chains
// interleaved in one k-loop; lists padded with -1 -> zero-row in d_ws.

typedef unsigned int uint32;

#define NNODES 8192
#define DF 128
#define WPR 256        // bitmap words per row
#define M 4            // nodes per block
#define CAP 192        // neighbor list cap (deg ~ Poisson(32); max row ~70)

__global__ void edge_scatter(const int* __restrict__ ei, int E,
                             uint32* __restrict__ bm) {
    int e = blockIdx.x * blockDim.x + threadIdx.x;
    if (e >= E) return;
    int src = ei[e];        // edge_index[0][e]
    int dst = ei[E + e];    // edge_index[1][e]
    atomicOr(&bm[(size_t)src * WPR + (dst >> 5)], 1u << (dst & 31));
}

__global__ __launch_bounds__(128) void gcn_fused(
    const float* __restrict__ x,
    const uint32* __restrict__ bm,
    const float4* __restrict__ zrow,   // 128 zero floats (in d_ws, memset)
    const float* __restrict__ W,
    const float* __restrict__ b,
    float* __restrict__ out)
{
    __shared__ int nbr[M][CAP];
    __shared__ int cnt_s[M];
    __shared__ __align__(16) float part[M][4][DF];  // per-group partials (8 KB)
    __shared__ float agg[M][DF];

    const int t    = threadIdx.x;
    const int lane = t & 63;
    const int wv   = t >> 6;          // 0/1
    const int node0 = blockIdx.x * M;

    // ---- Phase A: one wave per bitmap row; prefix-sum offsets, no atomics.
    #pragma unroll
    for (int pass = 0; pass < 2; ++pass) {
        const int m = pass * 2 + wv;
        const uint32* r = bm + (size_t)(node0 + m) * WPR;
        uint32 w0 = r[4 * lane + 0], w1 = r[4 * lane + 1],
               w2 = r[4 * lane + 2], w3 = r[4 * lane + 3];
        int c = __popc(w0) + __popc(w1) + __popc(w2) + __popc(w3);
        int v = c;                                   // inclusive wave scan
        #pragma unroll
        for (int d = 1; d < 64; d <<= 1) {
            int up = __shfl_up(v, d);
            if (lane >= d) v += up;
        }
        int off = v - c;                             // exclusive prefix
        if (lane == 63) cnt_s[m] = v;
        uint32 ws[4] = {w0, w1, w2, w3};
        #pragma unroll
        for (int q = 0; q < 4; ++q) {
            uint32 word = ws[q];
            int base = (4 * lane + q) << 5;
            while (word) {
                int bit = __ffs(word) - 1; word &= word - 1;
                if (off < CAP) nbr[m][off] = base + bit;
                off++;
            }
        }
    }
    __syncthreads();

    const int c0 = cnt_s[0], c1 = cnt_s[1], c2 = cnt_s[2], c3 = cnt_s[3];
    int Lmax = max(max(c0, c1), max(c2, c3));
    const bool overflow = (Lmax > CAP);              // statistically never
    int L = (min(Lmax, CAP) + 3) & ~3;               // pad to multiple of 4

    // Pad lists with -1 (sentinel -> zero row).
    for (int m = 0; m < M; ++m) {
        int cm = min(cnt_s[m], CAP);
        for (int k = cm + t; k < L; k += 128) nbr[m][k] = -1;
    }
    __syncthreads();

    if (!overflow) {
        // ---- Phase B: float4 gather. group g handles neighbors k===g (mod 4);
        // all M chains interleaved per iteration -> 4 loads in flight/thread.
        const int g = t >> 5;       // 0..3
        const int c = t & 31;       // float4 chunk
        const float4* x4 = (const float4*)x;

        float4 acc[M];
        #pragma unroll
        for (int m = 0; m < M; ++m) acc[m] = make_float4(0.f, 0.f, 0.f, 0.f);

        for (int k = g; k < L; k += 4) {
            #pragma unroll
            for (int m = 0; m < M; ++m) {
                int j = nbr[m][k];
                const float4* p = (j >= 0) ? (x4 + (size_t)j * (DF / 4) + c)
                                           : (zrow + c);
                float4 vx = *p;
                acc[m].x += vx.x; acc[m].y += vx.y;
                acc[m].z += vx.z; acc[m].w += vx.w;
            }
        }

        #pragma unroll
        for (int m = 0; m < M; ++m)
            *(float4*)&part[m][g][c * 4] = acc[m];
        __syncthreads();

        // Reduce groups, add eye, normalize.
        #pragma unroll
        for (int m = 0; m < M; ++m) {
            float s = part[m][0][t] + part[m][1][t]
                    + part[m][2][t] + part[m][3][t];
            s += x[(size_t)(node0 + m) * DF + t];    // self-loop on top
            agg[m][t] = s / (float)(1 + cnt_s[m]);
        }
    } else {
        // Fallback (correctness-safe, never expected): uniform bitmap rescan.
        for (int m = 0; m < M; ++m) {
            const uint32* r = bm + (size_t)(node0 + m) * WPR;
            float acc = x[(size_t)(node0 + m) * DF + t];
            for (int w = 0; w < WPR; ++w) {
                uint32 word = r[w];
                int base = w << 5;
                while (word) {
                    int bit = __ffs(word) - 1; word &= word - 1;
                    acc += x[(size_t)(base + bit) * DF + t];
                }
            }
            agg[m][t] = acc / (float)(1 + cnt_s[m]);
        }
    }
    __syncthreads();

    // ---- Phase C: fused linear. Thread t owns out dim t for all M nodes.
    const float4* Wrow = (const float4*)(W + (size_t)t * DF);
    float bias = b[t];
    float sum[M];
    #pragma unroll
    for (int m = 0; m < M; ++m) sum[m] = bias;

    #pragma unroll 8
    for (int c4 = 0; c4 < DF / 4; ++c4) {
        float4 wvv = Wrow[c4];
        #pragma unroll
        for (int m = 0; m < M; ++m) {
            sum[m] += wvv.x * agg[m][c4 * 4 + 0] + wvv.y * agg[m][c4 * 4 + 1]
                    + wvv.z * agg[m][c4 * 4 + 2] + wvv.w * agg[m][c4 * 4 + 3];
        }
    }
    #pragma unroll
    for (int m = 0; m < M; ++m)
        out[(size_t)(node0 + m) * DF + t] = sum[m];
}

extern "C" void kernel_launch(void* const* d_in, const int* in_sizes, int n_in,
                              void* d_out, int out_size, void* d_ws, size_t ws_size,
                              hipStream_t stream) {
    const float* x = (const float*)d_in[0];
    const int*  ei = (const int*)d_in[1];
    const float* W = (const float*)d_in[2];
    const float* b = (const float*)d_in[3];
    float* out = (float*)d_out;

    uint32* bm = (uint32*)d_ws;
    const size_t bm_bytes = (size_t)NNODES * WPR * sizeof(uint32);   // 8 MB
    const float4* zrow = (const float4*)((char*)d_ws + bm_bytes);    // 512 B zeros
    const int E = in_sizes[1] / 2;

    // d_ws is re-poisoned before every launch: zero bitmap + zero-row.
    hipMemsetAsync(d_ws, 0, bm_bytes + DF * sizeof(float), stream);

    edge_scatter<<<dim3((E + 255) / 256), dim3(256), 0, stream>>>(ei, E, bm);
    gcn_fused<<<dim3(NNODES / M), dim3(128), 0, stream>>>(x, bm, zrow, W, b, out);
}